// Round 7
// baseline (71.593 us; speedup 1.0000x reference)
//
#include <hip/hip_runtime.h>
#include <hip/hip_bf16.h>

// BasicBlock (ReActNet) fused pipeline, MI355X gfx950.  R7 = R6 fusion with
// the residual-x numerics fix: epilogue-1 reads x in f32 NCHW (as R5 did)
// instead of a bf16 NHWC copy -- sign(out1+b21) must see the exact out1.
// One fused kernel: conv3x3 (fp8 sign MFMA) -> BN+res+PReLU -> act2 in LDS
// -> conv1x1 -> BN+res+PReLU -> NCHW f32 out. Counted vmcnt(4) B-pipeline.

typedef unsigned short u16;
typedef unsigned char  u8;
typedef unsigned int   u32;
typedef float f32x4 __attribute__((ext_vector_type(4)));

#define GLD16(gsrc, ldst) \
  __builtin_amdgcn_global_load_lds((__attribute__((address_space(1))) void*)(gsrc), \
                                   (__attribute__((address_space(3))) void*)(ldst), 16, 0, 0)

__device__ __forceinline__ float b2f(u16 u) {
  union { unsigned int i; float f; } c; c.i = ((unsigned int)u) << 16; return c.f;
}
__device__ __forceinline__ u16 f2b(float f) {
  unsigned int u = __builtin_bit_cast(unsigned int, f);
  unsigned int r = (u + 0x7FFFu + ((u >> 16) & 1u)) >> 16;   // RNE
  return (u16)r;
}
__device__ __forceinline__ u8 f2sign8(float v) {   // fp8 e4m3 of sign(v)
  return (v > 0.f) ? 0x38 : ((v < 0.f) ? 0xB8 : 0x00);
}

// ---------------- prep: fp8 sign weights, fold scale*BN, loss ----------------
__global__ __launch_bounds__(256) void prep_kernel(
    const float* __restrict__ w1, const float* __restrict__ w2,
    const float* __restrict__ g1, const float* __restrict__ be1,
    const float* __restrict__ m1, const float* __restrict__ v1,
    const float* __restrict__ g2, const float* __restrict__ be2,
    const float* __restrict__ m2, const float* __restrict__ v2,
    u8* __restrict__ wsgn1, u8* __restrict__ wsgn2,
    float* __restrict__ ab,
    float* __restrict__ lossdst, const float* __restrict__ lossin)
{
  __shared__ float red[256];
  const int t = threadIdx.x;
  const int blk = blockIdx.x;
  float s = 0.f;
  if (blk < 256) {                       // w1: [o][ci][3x3] -> wsgn1[o][tap*256 + ci]
    const int o = blk;
    for (int jj = t; jj < 2304; jj += 256) {
      float v = w1[o * 2304 + jj];
      s += fabsf(v);
      int ci = jj / 9, tap = jj % 9;
      wsgn1[o * 2304 + tap * 256 + ci] = f2sign8(v);
    }
  } else {                               // w2: [o][ci] -> wsgn2[o][ci]
    const int o = blk - 256;
    float v = w2[o * 256 + t];
    s = fabsf(v);
    wsgn2[o * 256 + t] = f2sign8(v);
  }
  red[t] = s;
  __syncthreads();
  for (int st = 128; st > 0; st >>= 1) { if (t < st) red[t] += red[t + st]; __syncthreads(); }
  if (t == 0) {
    if (blk < 256) {
      const int o = blk;
      float scale = red[0] / 2304.f;
      float inv = g1[o] / sqrtf(v1[o] + 1e-5f);
      ab[o]       = scale * inv;                 // alpha1
      ab[256 + o] = be1[o] - m1[o] * inv;        // beta1
    } else {
      const int o = blk - 256;
      float scale = red[0] / 256.f;
      float inv = g2[o] / sqrtf(v2[o] + 1e-5f);
      ab[512 + o] = scale * inv;                 // alpha2
      ab[768 + o] = be2[o] - m2[o] * inv;        // beta2
    }
  }
  if (blk == 0 && t == 0) lossdst[0] = lossin[0];
}

// ------- act1 = fp8sign(x + b11), NCHW f32 -> PADDED (b,30,30,256) fp8; zero borders -------
__global__ __launch_bounds__(256) void act1_kernel(
    const float* __restrict__ x, const float* __restrict__ b11, u8* __restrict__ act1pad)
{
  __shared__ u8 lds8[112 * 64];
  const int t = threadIdx.x;
  const int pxgrp = blockIdx.x;        // 7 groups of 112 px (4 rows)
  const int c0 = blockIdx.y * 64;      // 4 ch groups
  const int img = blockIdx.z;
  const int p0 = pxgrp * 112;
  const float* xb = x + (size_t)img * 200704;
#pragma unroll
  for (int it = 0; it < 7; ++it) {     // read x coalesced, sign->fp8, LDS[p][c]
    int flat = it * 256 + t;           // c:64 x p4:28
    int c = flat / 28;
    int p = (flat % 28) * 4;
    float4 v4 = *(const float4*)(xb + (size_t)(c0 + c) * 784 + p0 + p);
    float bb = b11[c0 + c];
    lds8[(p + 0) * 64 + c] = f2sign8(v4.x + bb);
    lds8[(p + 1) * 64 + c] = f2sign8(v4.y + bb);
    lds8[(p + 2) * 64 + c] = f2sign8(v4.z + bb);
    lds8[(p + 3) * 64 + c] = f2sign8(v4.w + bb);
  }
  __syncthreads();
#pragma unroll
  for (int it = 0; it < 7; ++it) {     // write padded NHWC fp8 (4B per thread)
    int flat = it * 256 + t;           // px:112 x c4:16
    int px = flat >> 4;
    int c4 = (flat & 15) * 4;
    u32 v = *(const u32*)(lds8 + px * 64 + c4);
    int pr = (px * 293) >> 13;         // px/28
    int pc = px - 28 * pr;
    size_t dst = ((size_t)img * 900 + (size_t)(pxgrp * 4 + 1 + pr) * 30 + 1 + pc) * 256 + c0 + c4;
    *(u32*)(act1pad + dst) = v;
  }
  if (pxgrp == 0 && blockIdx.y == 0) { // zero this image's padded border
    for (int idx = t; idx < 116 * 64; idx += 256) {
      int bp = idx >> 6;
      int l4 = (idx & 63) * 4;
      int br, bc;
      if (bp < 30)      { br = 0;       bc = bp; }
      else if (bp < 60) { br = 29;      bc = bp - 30; }
      else if (bp < 88) { br = bp - 59; bc = 0; }
      else              { br = bp - 87; bc = 29; }
      *(u32*)(act1pad + ((size_t)img * 900 + br * 30 + bc) * 256 + l4) = 0u;
    }
  }
}

// ---------------- fused conv3x3 + conv1x1 block ----------------
__global__ __launch_bounds__(512, 2) void fused_kernel(
    const u8* __restrict__ act1pad, const float* __restrict__ x,
    const u8* __restrict__ wsgn1, const u8* __restrict__ wsgn2,
    const float* __restrict__ ab,
    const float* __restrict__ b12, const float* __restrict__ a1,
    const float* __restrict__ b13, const float* __restrict__ b21,
    const float* __restrict__ b22, const float* __restrict__ a2,
    const float* __restrict__ b23,
    float* __restrict__ dout)
{
  __shared__ __align__(16) u8 win[46080];       // 6 rows x 30 px x 256 ci (reused for act2)
  __shared__ __align__(16) u8 bB[3][16384];     // 256 rows x 64 B, triple buffer

  const int t = threadIdx.x;
  const int w = t >> 6;                // 0..7
  const int l = t & 63;
  const int lane16 = l & 15;
  const int lq = l >> 4;
  const int lq8 = lq * 8;
  const int wbase = w * 32;
  const int pxblk = blockIdx.x;        // 224
  const int img = pxblk / 7;
  const int rowgrp = pxblk % 7;

  // ---- epilogue params (f32 loads; drained by prologue vmcnt(0)) ----
  float al1[2], bt1[2], pA1[2], pS1[2], pB1[2], p21[2];
  float al2[2], bt2[2], pA2[2], pS2[2], pB2[2];
  int brow[2], bswz[2], brofs[2];
#pragma unroll
  for (int n = 0; n < 2; ++n) {
    int O = wbase + n * 16 + lane16;
    al1[n] = ab[O];       bt1[n] = ab[256 + O];
    al2[n] = ab[512 + O]; bt2[n] = ab[768 + O];
    pA1[n] = b12[O]; pS1[n] = a1[O]; pB1[n] = b13[O]; p21[n] = b21[O];
    pA2[n] = b22[O]; pS2[n] = a2[O]; pB2[n] = b23[O];
    brow[n] = O;
    bswz[n] = (O & 3) << 4;
    brofs[n] = O * 64;
  }

  // A geometry: basepix in 30-wide padded window rows
  int basepix[7], pb1[7], x71[7];
#pragma unroll
  for (int m = 0; m < 7; ++m) {
    int pm = m * 16 + lane16;
    int r = (pm * 293) >> 13;          // pm/28
    basepix[m] = r * 30 + (pm - 28 * r);
    pb1[m] = pm << 8;                  // conv1x1: act2 is output-pixel-indexed
    x71[m] = (pm & 7) << 4;
  }

  char* wl = (char*)win;
  char* bb = (char*)&bB[0][0];

  f32x4 acc[7][2];
  f32x4 zero4 = {0.f, 0.f, 0.f, 0.f};
#pragma unroll
  for (int m = 0; m < 7; ++m) { acc[m][0] = zero4; acc[m][1] = zero4; }

  auto STAGE_B = [&](int buf, const u8* wsrc, int kbytes, int s) {  // 2 GLD16/thread
#pragma unroll
    for (int i = 0; i < 2; ++i) {
      int c = i * 512 + t;             // 1024 chunks = 256 rows x 4
      int row = c >> 2;
      int j = c & 3;
      const char* src = (const char*)wsrc + (size_t)row * kbytes + s * 64 + ((j ^ (row & 3)) << 4);
      GLD16(src, bb + buf * 16384 + c * 16);
    }
  };

  auto COMPUTE3 = [&](int buf, int s) {
    int tap = s >> 2;
    int ci0 = (s & 3) << 6;
    int ti = (tap * 11) >> 5;          // tap/3
    int tapoff = ti * 30 + (tap - 3 * ti);
    const char* sB = bb + buf * 16384;
    int pb[7], x7[7];
#pragma unroll
    for (int m = 0; m < 7; ++m) {
      int pix = basepix[m] + tapoff;
      pb[m] = pix << 8;
      x7[m] = (pix & 7) << 4;
    }
#pragma unroll
    for (int sl = 0; sl < 2; ++sl) {
      int kin = ci0 + sl * 32 + lq8;
      int kb = sl * 32 + lq8;
      long bv0 = *(const long*)(sB + brofs[0] + (kb ^ bswz[0]));
      long bv1 = *(const long*)(sB + brofs[1] + (kb ^ bswz[1]));
      long av[7];
#pragma unroll
      for (int m = 0; m < 7; ++m)
        av[m] = *(const long*)(wl + pb[m] + (kin ^ x7[m]));
#pragma unroll
      for (int m = 0; m < 7; ++m) {
        acc[m][0] = __builtin_amdgcn_mfma_f32_16x16x32_fp8_fp8(av[m], bv0, acc[m][0], 0, 0, 0);
        acc[m][1] = __builtin_amdgcn_mfma_f32_16x16x32_fp8_fp8(av[m], bv1, acc[m][1], 0, 0, 0);
      }
    }
  };

  auto COMPUTE1 = [&](int buf, int sp) {
    const char* sB = bb + buf * 16384;
#pragma unroll
    for (int sl = 0; sl < 2; ++sl) {
      int kin = sp * 64 + sl * 32 + lq8;
      int kb = sl * 32 + lq8;
      long bv0 = *(const long*)(sB + brofs[0] + (kb ^ bswz[0]));
      long bv1 = *(const long*)(sB + brofs[1] + (kb ^ bswz[1]));
      long av[7];
#pragma unroll
      for (int m = 0; m < 7; ++m)
        av[m] = *(const long*)(wl + pb1[m] + (kin ^ x71[m]));
#pragma unroll
      for (int m = 0; m < 7; ++m) {
        acc[m][0] = __builtin_amdgcn_mfma_f32_16x16x32_fp8_fp8(av[m], bv0, acc[m][0], 0, 0, 0);
        acc[m][1] = __builtin_amdgcn_mfma_f32_16x16x32_fp8_fp8(av[m], bv1, acc[m][1], 0, 0, 0);
      }
    }
  };

  // ---- prologue: window (180 px) + B1 stages 0,1; full drain once ----
  const u8* winsrc = act1pad + ((size_t)img * 900 + (size_t)rowgrp * 120) * 256;
#pragma unroll
  for (int i = 0; i < 5; ++i) {
    int c = i * 512 + t;
    int pix = c >> 4, j = c & 15;
    GLD16((const char*)winsrc + pix * 256 + ((j ^ (pix & 7)) << 4), wl + c * 16);
  }
  if (t < 320) {
    int c = 2560 + t;
    int pix = c >> 4, j = c & 15;
    GLD16((const char*)winsrc + pix * 256 + ((j ^ (pix & 7)) << 4), wl + c * 16);
  }
  STAGE_B(0, wsgn1, 2304, 0);
  STAGE_B(1, wsgn1, 2304, 1);
  asm volatile("s_waitcnt vmcnt(0)" ::: "memory");
  __builtin_amdgcn_s_barrier();

  // ---- conv3x3: 36 phases, triple-buffer, counted vmcnt(4) ----
  int sb = 2, rb = 0;
#pragma unroll 1
  for (int s = 0; s < 34; ++s) {
    STAGE_B(sb, wsgn1, 2304, s + 2);
    sb = (sb == 2) ? 0 : sb + 1;
    asm volatile("s_waitcnt vmcnt(4)" ::: "memory");
    __builtin_amdgcn_s_barrier();
    COMPUTE3(rb, s);
    rb = (rb == 2) ? 0 : rb + 1;
    __builtin_amdgcn_s_barrier();
  }
  asm volatile("s_waitcnt vmcnt(2)" ::: "memory");
  __builtin_amdgcn_s_barrier();
  COMPUTE3(rb, 34);
  rb = (rb == 2) ? 0 : rb + 1;
  __builtin_amdgcn_s_barrier();
  asm volatile("s_waitcnt vmcnt(0)" ::: "memory");
  __builtin_amdgcn_s_barrier();
  COMPUTE3(rb, 35);
  __builtin_amdgcn_s_barrier();      // all waves done with window -> reuse for act2

  // ---- epilogue 1: out1 = BN(conv)+x (f32!) -> bias/PReLU/bias; act2 -> LDS ----
  u32 pk[7][2][2];
#pragma unroll
  for (int m = 0; m < 7; ++m) {
    int prow = m * 16 + lq * 4;
    int hwm = rowgrp * 112 + prow;
#pragma unroll
    for (int n = 0; n < 2; ++n) {
      float4 xr = *(const float4*)(x + ((size_t)(img * 256 + brow[n]) * 784 + hwm));
      float xv[4] = {xr.x, xr.y, xr.z, xr.w};
#pragma unroll
      for (int rp = 0; rp < 2; ++rp) {
        float o1v[2];
#pragma unroll
        for (int h = 0; h < 2; ++h) {
          int reg = rp * 2 + h;
          int pix = prow + reg;
          float v = acc[m][n][reg] * al1[n] + bt1[n] + xv[reg];
          float t1 = v + pA1[n];
          t1 = (t1 > 0.f) ? t1 : pS1[n] * t1;
          o1v[h] = t1 + pB1[n];
          wl[pix * 256 + (brow[n] ^ ((pix & 7) << 4))] = f2sign8(o1v[h] + p21[n]);
        }
        pk[m][n][rp] = (u32)f2b(o1v[0]) | ((u32)f2b(o1v[1]) << 16);
      }
    }
  }
  // re-zero accumulators for conv1x1
#pragma unroll
  for (int m = 0; m < 7; ++m) { acc[m][0] = zero4; acc[m][1] = zero4; }

  asm volatile("s_waitcnt vmcnt(0)" ::: "memory");   // x reads retired -> VM FIFO clean
  STAGE_B(0, wsgn2, 256, 0);
  STAGE_B(1, wsgn2, 256, 1);
  asm volatile("s_waitcnt lgkmcnt(0)" ::: "memory"); // act2 LDS stores complete
  __builtin_amdgcn_s_barrier();

  // ---- conv1x1: 4 phases ----
  // sp=0
  STAGE_B(2, wsgn2, 256, 2);
  asm volatile("s_waitcnt vmcnt(4)" ::: "memory");
  __builtin_amdgcn_s_barrier();
  COMPUTE1(0, 0);
  __builtin_amdgcn_s_barrier();
  // sp=1
  STAGE_B(0, wsgn2, 256, 3);
  asm volatile("s_waitcnt vmcnt(4)" ::: "memory");
  __builtin_amdgcn_s_barrier();
  COMPUTE1(1, 1);
  __builtin_amdgcn_s_barrier();
  // sp=2
  asm volatile("s_waitcnt vmcnt(2)" ::: "memory");
  __builtin_amdgcn_s_barrier();
  COMPUTE1(2, 2);
  __builtin_amdgcn_s_barrier();
  // sp=3
  asm volatile("s_waitcnt vmcnt(0)" ::: "memory");
  __builtin_amdgcn_s_barrier();
  COMPUTE1(0, 3);

  // ---- epilogue 2: out2 -> dout NCHW f32 ----
#pragma unroll
  for (int m = 0; m < 7; ++m) {
    int hwm = rowgrp * 112 + m * 16 + lq * 4;
#pragma unroll
    for (int n = 0; n < 2; ++n) {
      int O = brow[n];
      float r4v[4];
#pragma unroll
      for (int rp = 0; rp < 2; ++rp) {
        float res[2];
        res[0] = b2f((u16)(pk[m][n][rp] & 0xFFFF));
        res[1] = b2f((u16)(pk[m][n][rp] >> 16));
#pragma unroll
        for (int h = 0; h < 2; ++h) {
          int reg = rp * 2 + h;
          float v = acc[m][n][reg] * al2[n] + bt2[n] + res[h];
          float t1 = v + pA2[n];
          t1 = (t1 > 0.f) ? t1 : pS2[n] * t1;
          r4v[reg] = t1 + pB2[n];
        }
      }
      float4 r4 = {r4v[0], r4v[1], r4v[2], r4v[3]};
      *(float4*)(dout + ((size_t)(img * 256 + O)) * 784 + hwm) = r4;
    }
  }
}

// ---------------- launcher ----------------
extern "C" void kernel_launch(void* const* d_in, const int* in_sizes, int n_in,
                              void* d_out, int out_size, void* d_ws, size_t ws_size,
                              hipStream_t stream) {
  const float* x    = (const float*)d_in[0];
  const float* loss = (const float*)d_in[1];
  const float* b11  = (const float*)d_in[2];
  const float* b12  = (const float*)d_in[3];
  const float* b13  = (const float*)d_in[4];
  const float* b21  = (const float*)d_in[5];
  const float* b22  = (const float*)d_in[6];
  const float* b23  = (const float*)d_in[7];
  const float* w1   = (const float*)d_in[8];
  const float* w2   = (const float*)d_in[9];
  const float* g1   = (const float*)d_in[10];
  const float* be1  = (const float*)d_in[11];
  const float* m1   = (const float*)d_in[12];
  const float* v1   = (const float*)d_in[13];
  const float* g2   = (const float*)d_in[14];
  const float* be2  = (const float*)d_in[15];
  const float* m2   = (const float*)d_in[16];
  const float* v2   = (const float*)d_in[17];
  const float* a1   = (const float*)d_in[18];
  const float* a2   = (const float*)d_in[19];

  char* ws = (char*)d_ws;
  u8*    act1pad = (u8*)(ws + 0ull);            // fp8 (32,30,30,256) = 7,372,800
  u8*    wsgn1f8 = (u8*)(ws + 7372800ull);      // fp8 (256,2304)
  u8*    wsgn2f8 = (u8*)(ws + 7962624ull);      // fp8 (256,256)
  float* ab      = (float*)(ws + 8028160ull);   // 4 x 256 f32

  float* out = (float*)d_out;

  prep_kernel<<<512, 256, 0, stream>>>(w1, w2, g1, be1, m1, v1, g2, be2, m2, v2,
                                       wsgn1f8, wsgn2f8, ab, out + (out_size - 1), loss);
  act1_kernel<<<dim3(7, 4, 32), 256, 0, stream>>>(x, b11, act1pad);
  fused_kernel<<<224, 512, 0, stream>>>(act1pad, x, wsgn1f8, wsgn2f8, ab,
                                        b12, a1, b13, b21, b22, a2, b23, out);
}

// Round 8
// 63.172 us; speedup vs baseline: 1.1333x; 1.1333x over previous
//
#include <hip/hip_runtime.h>
#include <hip/hip_bf16.h>

// BasicBlock (ReActNet) fused pipeline, MI355X gfx950.  R8:
// B (weights) moved OUT of LDS into per-wave VGPRs via coalesced global loads
// from a phase-major transposed layout [phase][slot][O][8B] -- removes the
// global_load_lds B-staging path (~22B/cy/CU) and ALL K-loop barriers.
// A-window (45KB fp8) staged once per block in LDS. conv3x3+conv1x1 fused;
// act2 handed off via LDS with 4-bit slot swizzle. fp8 e4m3 exact-sign MFMA.

typedef unsigned short u16;
typedef unsigned char  u8;
typedef unsigned int   u32;
typedef unsigned long long u64;
typedef float f32x4 __attribute__((ext_vector_type(4)));

#define GLD16(gsrc, ldst) \
  __builtin_amdgcn_global_load_lds((__attribute__((address_space(1))) void*)(gsrc), \
                                   (__attribute__((address_space(3))) void*)(ldst), 16, 0, 0)

__device__ __forceinline__ float b2f(u16 u) {
  union { unsigned int i; float f; } c; c.i = ((unsigned int)u) << 16; return c.f;
}
__device__ __forceinline__ u16 f2b(float f) {
  unsigned int u = __builtin_bit_cast(unsigned int, f);
  unsigned int r = (u + 0x7FFFu + ((u >> 16) & 1u)) >> 16;   // RNE
  return (u16)r;
}
__device__ __forceinline__ u8 f2sign8(float v) {   // fp8 e4m3 of sign(v)
  return (v > 0.f) ? 0x38 : ((v < 0.f) ? 0xB8 : 0x00);
}

// ---- prep: fp8 sign weights in phase-major [phase][slot(8)][O(256)][8B]; BN fold; loss ----
// conv3x3 phase s (0..35): tap = s>>2, ci-range = (s&3)*64 .. +64; slot = (ci>>3)&7.
// dst byte = (tap*32 + (ci>>3))*2048 + o*8 + (ci&7).   conv1x1: same minus tap.
__global__ __launch_bounds__(256) void prep_kernel(
    const float* __restrict__ w1, const float* __restrict__ w2,
    const float* __restrict__ g1, const float* __restrict__ be1,
    const float* __restrict__ m1, const float* __restrict__ v1,
    const float* __restrict__ g2, const float* __restrict__ be2,
    const float* __restrict__ m2, const float* __restrict__ v2,
    u8* __restrict__ w1T, u8* __restrict__ w2T,
    float* __restrict__ ab,
    float* __restrict__ lossdst, const float* __restrict__ lossin)
{
  __shared__ float red[256];
  const int t = threadIdx.x;
  const int blk = blockIdx.x;
  float s = 0.f;
  if (blk < 256) {                       // w1: [o][ci][3x3]
    const int o = blk;
    for (int it = t; it < 288; it += 256) {   // (tap, ci-octet)
      int tap = it >> 5, ci8 = it & 31;
      u64 pack = 0;
#pragma unroll
      for (int k = 0; k < 8; ++k) {
        float v = w1[o * 2304 + (ci8 * 8 + k) * 9 + tap];
        s += fabsf(v);
        pack |= ((u64)f2sign8(v)) << (8 * k);
      }
      *(u64*)(w1T + (size_t)(tap * 32 + ci8) * 2048 + o * 8) = pack;
    }
  } else {                               // w2: [o][ci]
    const int o = blk - 256;
    if (t < 32) {
      u64 pack = 0;
#pragma unroll
      for (int k = 0; k < 8; ++k) {
        float v = w2[o * 256 + t * 8 + k];
        s += fabsf(v);
        pack |= ((u64)f2sign8(v)) << (8 * k);
      }
      *(u64*)(w2T + (size_t)t * 2048 + o * 8) = pack;
    }
  }
  red[t] = s;
  __syncthreads();
  for (int st = 128; st > 0; st >>= 1) { if (t < st) red[t] += red[t + st]; __syncthreads(); }
  if (t == 0) {
    if (blk < 256) {
      const int o = blk;
      float scale = red[0] / 2304.f;
      float inv = g1[o] / sqrtf(v1[o] + 1e-5f);
      ab[o]       = scale * inv;                 // alpha1
      ab[256 + o] = be1[o] - m1[o] * inv;        // beta1
    } else {
      const int o = blk - 256;
      float scale = red[0] / 256.f;
      float inv = g2[o] / sqrtf(v2[o] + 1e-5f);
      ab[512 + o] = scale * inv;                 // alpha2
      ab[768 + o] = be2[o] - m2[o] * inv;        // beta2
    }
  }
  if (blk == 0 && t == 0) lossdst[0] = lossin[0];
}

// ------- act1 = fp8sign(x + b11), NCHW f32 -> PADDED (b,30,30,256) fp8; zero borders -------
__global__ __launch_bounds__(256) void act1_kernel(
    const float* __restrict__ x, const float* __restrict__ b11, u8* __restrict__ act1pad)
{
  __shared__ u8 lds8[112 * 64];
  const int t = threadIdx.x;
  const int pxgrp = blockIdx.x;
  const int c0 = blockIdx.y * 64;
  const int img = blockIdx.z;
  const int p0 = pxgrp * 112;
  const float* xb = x + (size_t)img * 200704;
#pragma unroll
  for (int it = 0; it < 7; ++it) {
    int flat = it * 256 + t;           // c:64 x p4:28
    int c = flat / 28;
    int p = (flat % 28) * 4;
    float4 v4 = *(const float4*)(xb + (size_t)(c0 + c) * 784 + p0 + p);
    float bb = b11[c0 + c];
    lds8[(p + 0) * 64 + c] = f2sign8(v4.x + bb);
    lds8[(p + 1) * 64 + c] = f2sign8(v4.y + bb);
    lds8[(p + 2) * 64 + c] = f2sign8(v4.z + bb);
    lds8[(p + 3) * 64 + c] = f2sign8(v4.w + bb);
  }
  __syncthreads();
#pragma unroll
  for (int it = 0; it < 7; ++it) {
    int flat = it * 256 + t;           // px:112 x c4:16
    int px = flat >> 4;
    int c4 = (flat & 15) * 4;
    u32 v = *(const u32*)(lds8 + px * 64 + c4);
    int pr = (px * 293) >> 13;         // px/28
    int pc = px - 28 * pr;
    size_t dst = ((size_t)img * 900 + (size_t)(pxgrp * 4 + 1 + pr) * 30 + 1 + pc) * 256 + c0 + c4;
    *(u32*)(act1pad + dst) = v;
  }
  if (pxgrp == 0 && blockIdx.y == 0) {
    for (int idx = t; idx < 116 * 64; idx += 256) {
      int bp = idx >> 6;
      int l4 = (idx & 63) * 4;
      int br, bc;
      if (bp < 30)      { br = 0;       bc = bp; }
      else if (bp < 60) { br = 29;      bc = bp - 30; }
      else if (bp < 88) { br = bp - 59; bc = 0; }
      else              { br = bp - 87; bc = 29; }
      *(u32*)(act1pad + ((size_t)img * 900 + br * 30 + bc) * 256 + l4) = 0u;
    }
  }
}

// ---------------- fused conv3x3 + conv1x1, register-B, barrier-free K-loop ----------------
__global__ __launch_bounds__(512, 2) void fused_kernel(
    const u8* __restrict__ act1pad, const float* __restrict__ x,
    const u8* __restrict__ w1T, const u8* __restrict__ w2T,
    const float* __restrict__ ab,
    const float* __restrict__ b12, const float* __restrict__ a1,
    const float* __restrict__ b13, const float* __restrict__ b21,
    const float* __restrict__ b22, const float* __restrict__ a2,
    const float* __restrict__ b23,
    float* __restrict__ dout)
{
  __shared__ __align__(16) u8 win[46080];   // 6 rows x 30 px x 256 ci; reused for act2

  const int t = threadIdx.x;
  const int w = t >> 6;                // 0..7
  const int l = t & 63;
  const int lane16 = l & 15;
  const int lq = l >> 4;
  const int O0 = w * 32 + lane16;      // out-ch for n=0 (n=1 adds 16)
  const int pxblk = blockIdx.x;        // 224
  const int img = pxblk / 7;
  const int rowgrp = pxblk % 7;

  // ---- epilogue params ----
  float al1[2], bt1[2], pA1[2], pS1[2], pB1[2], p21[2];
  float al2[2], bt2[2], pA2[2], pS2[2], pB2[2];
#pragma unroll
  for (int n = 0; n < 2; ++n) {
    int O = O0 + n * 16;
    al1[n] = ab[O];       bt1[n] = ab[256 + O];
    al2[n] = ab[512 + O]; bt2[n] = ab[768 + O];
    pA1[n] = b12[O]; pS1[n] = a1[O]; pB1[n] = b13[O]; p21[n] = b21[O];
    pA2[n] = b22[O]; pS2[n] = a2[O]; pB2[n] = b23[O];
  }

  // A geometry
  int basepix[7], pb1[7], x71[7];
#pragma unroll
  for (int m = 0; m < 7; ++m) {
    int pm = m * 16 + lane16;
    int r = (pm * 293) >> 13;          // pm/28
    basepix[m] = r * 30 + (pm - 28 * r);
    pb1[m] = pm << 8;
    x71[m] = (pm & 15) << 4;
  }

  char* wl = (char*)win;

  f32x4 acc[7][2];
  f32x4 zero4 = {0.f, 0.f, 0.f, 0.f};
#pragma unroll
  for (int m = 0; m < 7; ++m) { acc[m][0] = zero4; acc[m][1] = zero4; }

  // ---- prologue: stage A-window once (4-bit slot swizzle via pre-swizzled source) ----
  const u8* winsrc = act1pad + ((size_t)img * 900 + (size_t)rowgrp * 120) * 256;
#pragma unroll
  for (int i = 0; i < 5; ++i) {
    int c = i * 512 + t;
    int pix = c >> 4, j = c & 15;
    GLD16((const char*)winsrc + pix * 256 + ((j ^ (pix & 15)) << 4), wl + c * 16);
  }
  if (t < 320) {
    int c = 2560 + t;
    int pix = c >> 4, j = c & 15;
    GLD16((const char*)winsrc + pix * 256 + ((j ^ (pix & 15)) << 4), wl + c * 16);
  }
  asm volatile("s_waitcnt vmcnt(0)" ::: "memory");
  __builtin_amdgcn_s_barrier();

  // ---- register-B loaders (coalesced 128B segments; compiler-counted waits) ----
  auto LOADB3 = [&](long* dst, int s) {
    const char* base = (const char*)w1T + (size_t)s * 16384 + lq * 2048;
#pragma unroll
    for (int n = 0; n < 2; ++n)
#pragma unroll
      for (int sl = 0; sl < 2; ++sl)
        dst[n * 2 + sl] = *(const long*)(base + sl * 8192 + (O0 + n * 16) * 8);
  };
  auto LOADB1 = [&](long* dst, int sp) {
    const char* base = (const char*)w2T + (size_t)sp * 16384 + lq * 2048;
#pragma unroll
    for (int n = 0; n < 2; ++n)
#pragma unroll
      for (int sl = 0; sl < 2; ++sl)
        dst[n * 2 + sl] = *(const long*)(base + sl * 8192 + (O0 + n * 16) * 8);
  };

  auto COMP3 = [&](int s, const long* bv) {
    int tap = s >> 2;
    int ci0 = (s & 3) << 6;
    int ti = (tap * 11) >> 5;          // tap/3
    int tapoff = ti * 30 + (tap - 3 * ti);
#pragma unroll
    for (int sl = 0; sl < 2; ++sl) {
      int kin = ci0 + sl * 32 + lq * 8;
      long av[7];
#pragma unroll
      for (int m = 0; m < 7; ++m) {
        int wp = basepix[m] + tapoff;
        av[m] = *(const long*)(wl + wp * 256 + (kin ^ ((wp & 15) << 4)));
      }
#pragma unroll
      for (int m = 0; m < 7; ++m) {
        acc[m][0] = __builtin_amdgcn_mfma_f32_16x16x32_fp8_fp8(av[m], bv[sl],     acc[m][0], 0, 0, 0);
        acc[m][1] = __builtin_amdgcn_mfma_f32_16x16x32_fp8_fp8(av[m], bv[2 + sl], acc[m][1], 0, 0, 0);
      }
    }
  };
  auto COMP1 = [&](int sp, const long* bv) {
#pragma unroll
    for (int sl = 0; sl < 2; ++sl) {
      int kin = sp * 64 + sl * 32 + lq * 8;
      long av[7];
#pragma unroll
      for (int m = 0; m < 7; ++m)
        av[m] = *(const long*)(wl + pb1[m] + (kin ^ x71[m]));
#pragma unroll
      for (int m = 0; m < 7; ++m) {
        acc[m][0] = __builtin_amdgcn_mfma_f32_16x16x32_fp8_fp8(av[m], bv[sl],     acc[m][0], 0, 0, 0);
        acc[m][1] = __builtin_amdgcn_mfma_f32_16x16x32_fp8_fp8(av[m], bv[2 + sl], acc[m][1], 0, 0, 0);
      }
    }
  };

  // ---- conv3x3: 36 phases, 3-set register rotation, prefetch depth 2, NO barriers ----
  long b0[4], b1[4], b2[4];
  LOADB3(b0, 0); LOADB3(b1, 1);
#pragma unroll 1
  for (int i = 0; i < 12; ++i) {
    int s = i * 3;
    LOADB3(b2, s + 2); COMP3(s,     b0);
    LOADB3(b0, s + 3); COMP3(s + 1, b1);   // s+3..s+4 at i=11 read pad region (unused)
    LOADB3(b1, s + 4); COMP3(s + 2, b2);
  }
  __builtin_amdgcn_s_barrier();      // all waves done reading window -> reuse for act2

  // ---- epilogue 1: out1 = BN(conv)+x(f32) -> bias/PReLU/bias; act2 -> LDS; pk = bf16(out1) ----
  u32 pk[7][2][2];
#pragma unroll
  for (int m = 0; m < 7; ++m) {
    int prow = m * 16 + lq * 4;
    int hwm = rowgrp * 112 + prow;
#pragma unroll
    for (int n = 0; n < 2; ++n) {
      int O = O0 + n * 16;
      float4 xr = *(const float4*)(x + ((size_t)(img * 256 + O) * 784 + hwm));
      float xv[4] = {xr.x, xr.y, xr.z, xr.w};
#pragma unroll
      for (int rp = 0; rp < 2; ++rp) {
        float o1v[2];
#pragma unroll
        for (int h = 0; h < 2; ++h) {
          int reg = rp * 2 + h;
          int pix = prow + reg;
          float v = acc[m][n][reg] * al1[n] + bt1[n] + xv[reg];
          float t1 = v + pA1[n];
          t1 = (t1 > 0.f) ? t1 : pS1[n] * t1;
          o1v[h] = t1 + pB1[n];
          wl[pix * 256 + (O ^ ((pix & 15) << 4))] = f2sign8(o1v[h] + p21[n]);
        }
        pk[m][n][rp] = (u32)f2b(o1v[0]) | ((u32)f2b(o1v[1]) << 16);
      }
    }
  }
#pragma unroll
  for (int m = 0; m < 7; ++m) { acc[m][0] = zero4; acc[m][1] = zero4; }

  asm volatile("s_waitcnt lgkmcnt(0)" ::: "memory");   // act2 LDS stores complete
  __builtin_amdgcn_s_barrier();

  // ---- conv1x1: 4 phases, 2-set rotation, no barriers ----
  long c0[4], c1[4];
  LOADB1(c0, 0); LOADB1(c1, 1);
  COMP1(0, c0); LOADB1(c0, 2);
  COMP1(1, c1); LOADB1(c1, 3);
  COMP1(2, c0);
  COMP1(3, c1);

  // ---- epilogue 2: out2 -> dout NCHW f32 ----
#pragma unroll
  for (int m = 0; m < 7; ++m) {
    int hwm = rowgrp * 112 + m * 16 + lq * 4;
#pragma unroll
    for (int n = 0; n < 2; ++n) {
      int O = O0 + n * 16;
      float r4v[4];
#pragma unroll
      for (int rp = 0; rp < 2; ++rp) {
        float res[2];
        res[0] = b2f((u16)(pk[m][n][rp] & 0xFFFF));
        res[1] = b2f((u16)(pk[m][n][rp] >> 16));
#pragma unroll
        for (int h = 0; h < 2; ++h) {
          int reg = rp * 2 + h;
          float v = acc[m][n][reg] * al2[n] + bt2[n] + res[h];
          float t1 = v + pA2[n];
          t1 = (t1 > 0.f) ? t1 : pS2[n] * t1;
          r4v[reg] = t1 + pB2[n];
        }
      }
      float4 r4 = {r4v[0], r4v[1], r4v[2], r4v[3]};
      *(float4*)(dout + ((size_t)(img * 256 + O)) * 784 + hwm) = r4;
    }
  }
}

// ---------------- launcher ----------------
extern "C" void kernel_launch(void* const* d_in, const int* in_sizes, int n_in,
                              void* d_out, int out_size, void* d_ws, size_t ws_size,
                              hipStream_t stream) {
  const float* x    = (const float*)d_in[0];
  const float* loss = (const float*)d_in[1];
  const float* b11  = (const float*)d_in[2];
  const float* b12  = (const float*)d_in[3];
  const float* b13  = (const float*)d_in[4];
  const float* b21  = (const float*)d_in[5];
  const float* b22  = (const float*)d_in[6];
  const float* b23  = (const float*)d_in[7];
  const float* w1   = (const float*)d_in[8];
  const float* w2   = (const float*)d_in[9];
  const float* g1   = (const float*)d_in[10];
  const float* be1  = (const float*)d_in[11];
  const float* m1   = (const float*)d_in[12];
  const float* v1   = (const float*)d_in[13];
  const float* g2   = (const float*)d_in[14];
  const float* be2  = (const float*)d_in[15];
  const float* m2   = (const float*)d_in[16];
  const float* v2   = (const float*)d_in[17];
  const float* a1   = (const float*)d_in[18];
  const float* a2   = (const float*)d_in[19];

  char* ws = (char*)d_ws;
  u8*    act1pad = (u8*)(ws + 0ull);           // fp8 (32,30,30,256) = 7,372,800
  u8*    w1T     = (u8*)(ws + 7372800ull);     // 38 phases x 16KB = 622,592 (36 used + 2 pad)
  u8*    w2T     = (u8*)(ws + 7995392ull);     // 4 phases x 16KB = 65,536
  float* ab      = (float*)(ws + 8060928ull);  // 4 x 256 f32

  float* out = (float*)d_out;

  prep_kernel<<<512, 256, 0, stream>>>(w1, w2, g1, be1, m1, v1, g2, be2, m2, v2,
                                       w1T, w2T, ab, out + (out_size - 1), loss);
  act1_kernel<<<dim3(7, 4, 32), 256, 0, stream>>>(x, b11, act1pad);
  fused_kernel<<<224, 512, 0, stream>>>(act1pad, x, w1T, w2T, ab,
                                        b12, a1, b13, b21, b22, a2, b23, out);
}

// Round 9
// 59.831 us; speedup vs baseline: 1.1966x; 1.0558x over previous
//
#include <hip/hip_runtime.h>
#include <hip/hip_bf16.h>

// BasicBlock (ReActNet) fused pipeline, MI355X gfx950.  R9 = R8 +
// (1) A-fragment register double-buffer (prefetch next phase's LDS reads
//     under current phase's MFMAs -- hides ds latency at 2 waves/SIMD),
// (2) b128 paired A-reads via pos-permuted window layout
//     pos(ci) = (ci&0xC0) + lq*16 + sl*8 + b  (lq=(ci>>3)&3, sl=(ci>>5)&1, b=ci&7)
//     so one ds_read_b128 yields both sl fragments (7 DS ops/phase not 14),
// (3) prep: w1 staged via float4->LDS (coalesced) before packing.

typedef unsigned short u16;
typedef unsigned char  u8;
typedef unsigned int   u32;
typedef unsigned long long u64;
typedef float f32x4 __attribute__((ext_vector_type(4)));
typedef long  long2v __attribute__((ext_vector_type(2)));

#define GLD16(gsrc, ldst) \
  __builtin_amdgcn_global_load_lds((__attribute__((address_space(1))) void*)(gsrc), \
                                   (__attribute__((address_space(3))) void*)(ldst), 16, 0, 0)

__device__ __forceinline__ float b2f(u16 u) {
  union { unsigned int i; float f; } c; c.i = ((unsigned int)u) << 16; return c.f;
}
__device__ __forceinline__ u16 f2b(float f) {
  unsigned int u = __builtin_bit_cast(unsigned int, f);
  unsigned int r = (u + 0x7FFFu + ((u >> 16) & 1u)) >> 16;   // RNE
  return (u16)r;
}
__device__ __forceinline__ u8 f2sign8(float v) {   // fp8 e4m3 of sign(v)
  return (v > 0.f) ? 0x38 : ((v < 0.f) ? 0xB8 : 0x00);
}

// ---- prep: fp8 sign weights phase-major [phase][c8(8)][O(256)][8B]; BN fold; loss ----
__global__ __launch_bounds__(256) void prep_kernel(
    const float* __restrict__ w1, const float* __restrict__ w2,
    const float* __restrict__ g1, const float* __restrict__ be1,
    const float* __restrict__ m1, const float* __restrict__ v1,
    const float* __restrict__ g2, const float* __restrict__ be2,
    const float* __restrict__ m2, const float* __restrict__ v2,
    u8* __restrict__ w1T, u8* __restrict__ w2T,
    float* __restrict__ ab,
    float* __restrict__ lossdst, const float* __restrict__ lossin)
{
  __shared__ float wrow[2304];
  __shared__ float red[256];
  const int t = threadIdx.x;
  const int blk = blockIdx.x;
  float s = 0.f;
  if (blk < 256) {                       // w1 row o: stage coalesced, then pack
    const int o = blk;
    const float4* src = (const float4*)(w1 + o * 2304);
#pragma unroll
    for (int i = 0; i < 3; ++i) {
      int c = i * 256 + t;
      if (c < 576) {
        float4 v = src[c];
        wrow[c * 4 + 0] = v.x; wrow[c * 4 + 1] = v.y;
        wrow[c * 4 + 2] = v.z; wrow[c * 4 + 3] = v.w;
        s += fabsf(v.x) + fabsf(v.y) + fabsf(v.z) + fabsf(v.w);
      }
    }
  } else {                               // w2 row o: stage coalesced
    const int o = blk - 256;
    float v = w2[o * 256 + t];
    wrow[t] = v;
    s = fabsf(v);
  }
  red[t] = s;
  __syncthreads();
  for (int st = 128; st > 0; st >>= 1) { if (t < st) red[t] += red[t + st]; __syncthreads(); }
  if (blk < 256) {
    const int o = blk;
    for (int it = t; it < 288; it += 256) {   // (tap, ci-octet)
      int tap = it >> 5, ci8 = it & 31;
      u64 pack = 0;
#pragma unroll
      for (int k = 0; k < 8; ++k)
        pack |= ((u64)f2sign8(wrow[(ci8 * 8 + k) * 9 + tap])) << (8 * k);
      *(u64*)(w1T + (size_t)(tap * 32 + ci8) * 2048 + o * 8) = pack;
    }
    if (t == 0) {
      float scale = red[0] / 2304.f;
      float inv = g1[o] / sqrtf(v1[o] + 1e-5f);
      ab[o]       = scale * inv;
      ab[256 + o] = be1[o] - m1[o] * inv;
    }
  } else {
    const int o = blk - 256;
    if (t < 32) {
      u64 pack = 0;
#pragma unroll
      for (int k = 0; k < 8; ++k)
        pack |= ((u64)f2sign8(wrow[t * 8 + k])) << (8 * k);
      *(u64*)(w2T + (size_t)t * 2048 + o * 8) = pack;
    }
    if (t == 0) {
      float scale = red[0] / 256.f;
      float inv = g2[o] / sqrtf(v2[o] + 1e-5f);
      ab[512 + o] = scale * inv;
      ab[768 + o] = be2[o] - m2[o] * inv;
    }
  }
  if (blk == 0 && t == 0) lossdst[0] = lossin[0];
}

// ------- act1: NCHW f32 -> padded fp8 signs (b,30,30,256), POS-PERMUTED channel order -------
__global__ __launch_bounds__(256) void act1_kernel(
    const float* __restrict__ x, const float* __restrict__ b11, u8* __restrict__ act1pad)
{
  __shared__ u8 lds8[112 * 64];
  const int t = threadIdx.x;
  const int pxgrp = blockIdx.x;
  const int c0 = blockIdx.y * 64;
  const int img = blockIdx.z;
  const int p0 = pxgrp * 112;
  const float* xb = x + (size_t)img * 200704;
#pragma unroll
  for (int it = 0; it < 7; ++it) {
    int flat = it * 256 + t;           // c:64 x p4:28
    int c = flat / 28;
    int p = (flat % 28) * 4;
    float4 v4 = *(const float4*)(xb + (size_t)(c0 + c) * 784 + p0 + p);
    float bb = b11[c0 + c];
    lds8[(p + 0) * 64 + c] = f2sign8(v4.x + bb);
    lds8[(p + 1) * 64 + c] = f2sign8(v4.y + bb);
    lds8[(p + 2) * 64 + c] = f2sign8(v4.z + bb);
    lds8[(p + 3) * 64 + c] = f2sign8(v4.w + bb);
  }
  __syncthreads();
#pragma unroll
  for (int it = 0; it < 7; ++it) {
    int flat = it * 256 + t;           // px:112 x c4:16
    int px = flat >> 4;
    int c4 = (flat & 15) * 4;          // local ci, multiple of 4
    u32 v = *(const u32*)(lds8 + px * 64 + c4);
    int pos = (((c4 >> 3) & 3) << 4) | (((c4 >> 5) & 1) << 3) | (c4 & 7);  // pos-permute
    int pr = (px * 293) >> 13;         // px/28
    int pc = px - 28 * pr;
    size_t dst = ((size_t)img * 900 + (size_t)(pxgrp * 4 + 1 + pr) * 30 + 1 + pc) * 256 + c0 + pos;
    *(u32*)(act1pad + dst) = v;
  }
  if (pxgrp == 0 && blockIdx.y == 0) {
    for (int idx = t; idx < 116 * 64; idx += 256) {
      int bp = idx >> 6;
      int l4 = (idx & 63) * 4;
      int br, bc;
      if (bp < 30)      { br = 0;       bc = bp; }
      else if (bp < 60) { br = 29;      bc = bp - 30; }
      else if (bp < 88) { br = bp - 59; bc = 0; }
      else              { br = bp - 87; bc = 29; }
      *(u32*)(act1pad + ((size_t)img * 900 + br * 30 + bc) * 256 + l4) = 0u;
    }
  }
}

// ---------------- fused conv3x3 + conv1x1, register-B, A-reg double-buffer ----------------
__global__ __launch_bounds__(512, 2) void fused_kernel(
    const u8* __restrict__ act1pad, const float* __restrict__ x,
    const u8* __restrict__ w1T, const u8* __restrict__ w2T,
    const float* __restrict__ ab,
    const float* __restrict__ b12, const float* __restrict__ a1,
    const float* __restrict__ b13, const float* __restrict__ b21,
    const float* __restrict__ b22, const float* __restrict__ a2,
    const float* __restrict__ b23,
    float* __restrict__ dout)
{
  __shared__ __align__(16) u8 win[46080];   // 180 px x 256 B; reused for act2

  const int t = threadIdx.x;
  const int w = t >> 6;
  const int l = t & 63;
  const int lane16 = l & 15;
  const int lq = l >> 4;
  const int O0 = w * 32 + lane16;
  const int pxblk = blockIdx.x;        // 224
  const int img = pxblk / 7;
  const int rowgrp = pxblk % 7;

  float al1[2], bt1[2], pA1[2], pS1[2], pB1[2], p21[2];
  float al2[2], bt2[2], pA2[2], pS2[2], pB2[2];
  int posO[2];
#pragma unroll
  for (int n = 0; n < 2; ++n) {
    int O = O0 + n * 16;
    al1[n] = ab[O];       bt1[n] = ab[256 + O];
    al2[n] = ab[512 + O]; bt2[n] = ab[768 + O];
    pA1[n] = b12[O]; pS1[n] = a1[O]; pB1[n] = b13[O]; p21[n] = b21[O];
    pA2[n] = b22[O]; pS2[n] = a2[O]; pB2[n] = b23[O];
    posO[n] = (O & 0xC0) | (((O >> 3) & 3) << 4) | (((O >> 5) & 1) << 3) | (O & 7);
  }

  int basepix[7];
#pragma unroll
  for (int m = 0; m < 7; ++m) {
    int pm = m * 16 + lane16;
    int r = (pm * 293) >> 13;          // pm/28
    basepix[m] = r * 30 + (pm - 28 * r);
  }

  char* wl = (char*)win;

  f32x4 acc[7][2];
  f32x4 zero4 = {0.f, 0.f, 0.f, 0.f};
#pragma unroll
  for (int m = 0; m < 7; ++m) { acc[m][0] = zero4; acc[m][1] = zero4; }

  // ---- prologue: stage pos-ordered window once (inverse-swizzled source) ----
  const u8* winsrc = act1pad + ((size_t)img * 900 + (size_t)rowgrp * 120) * 256;
#pragma unroll
  for (int i = 0; i < 5; ++i) {
    int c = i * 512 + t;
    int pix = c >> 4, j = c & 15;
    GLD16((const char*)winsrc + pix * 256 + ((j ^ (pix & 15)) << 4), wl + c * 16);
  }
  if (t < 320) {
    int c = 2560 + t;
    int pix = c >> 4, j = c & 15;
    GLD16((const char*)winsrc + pix * 256 + ((j ^ (pix & 15)) << 4), wl + c * 16);
  }
  asm volatile("s_waitcnt vmcnt(0)" ::: "memory");
  __builtin_amdgcn_s_barrier();

  // ---- loaders / compute primitives ----
  auto LOADB3 = [&](long* dst, int s) {
    int sc = (s < 36) ? s : 0;
    const char* base = (const char*)w1T + (size_t)sc * 16384 + lq * 2048;
#pragma unroll
    for (int n = 0; n < 2; ++n)
#pragma unroll
      for (int sl = 0; sl < 2; ++sl)
        dst[n * 2 + sl] = *(const long*)(base + sl * 8192 + (O0 + n * 16) * 8);
  };
  auto LOADB1 = [&](long* dst, int sp) {
    const char* base = (const char*)w2T + (size_t)sp * 16384 + lq * 2048;
#pragma unroll
    for (int n = 0; n < 2; ++n)
#pragma unroll
      for (int sl = 0; sl < 2; ++sl)
        dst[n * 2 + sl] = *(const long*)(base + sl * 8192 + (O0 + n * 16) * 8);
  };
  auto DSA3 = [&](long2v* dst, int s) {      // 7 x ds_read_b128, phase s
    int tap = s >> 2;
    int ti = (tap * 11) >> 5;                // tap/3
    int tapoff = ti * 30 + (tap - 3 * ti);
    int base16 = (s & 3) * 64 + lq * 16;
#pragma unroll
    for (int m = 0; m < 7; ++m) {
      int wp = basepix[m] + tapoff;
      dst[m] = *(const long2v*)(wl + wp * 256 + (base16 ^ ((wp & 15) << 4)));
    }
  };
  auto DSA1 = [&](long2v* dst, int sp) {
    int base16 = sp * 64 + lq * 16;
#pragma unroll
    for (int m = 0; m < 7; ++m) {
      int pm = m * 16 + lane16;
      dst[m] = *(const long2v*)(wl + pm * 256 + (base16 ^ ((pm & 15) << 4)));
    }
  };
  auto COMP = [&](const long2v* a, const long* bv) {
#pragma unroll
    for (int m = 0; m < 7; ++m) {
      acc[m][0] = __builtin_amdgcn_mfma_f32_16x16x32_fp8_fp8(a[m][0], bv[0], acc[m][0], 0, 0, 0);
      acc[m][1] = __builtin_amdgcn_mfma_f32_16x16x32_fp8_fp8(a[m][0], bv[2], acc[m][1], 0, 0, 0);
      acc[m][0] = __builtin_amdgcn_mfma_f32_16x16x32_fp8_fp8(a[m][1], bv[1], acc[m][0], 0, 0, 0);
      acc[m][1] = __builtin_amdgcn_mfma_f32_16x16x32_fp8_fp8(a[m][1], bv[3], acc[m][1], 0, 0, 0);
    }
  };

  // ---- conv3x3: 36 phases, A reg-dbuf + B 3-set rotation, no barriers ----
  long2v A0[7], A1[7];
  long b0[4], b1[4], b2[4];
  DSA3(A0, 0); LOADB3(b0, 0); LOADB3(b1, 1);
#pragma unroll 1
  for (int i = 0; i < 6; ++i) {
    int p = i * 6;
    LOADB3(b2, p + 2); DSA3(A1, p + 1);                  COMP(A0, b0);
    LOADB3(b0, p + 3); DSA3(A0, p + 2);                  COMP(A1, b1);
    LOADB3(b1, p + 4); DSA3(A1, p + 3);                  COMP(A0, b2);
    LOADB3(b2, p + 5); DSA3(A0, p + 4);                  COMP(A1, b0);
    LOADB3(b0, p + 6); DSA3(A1, p + 5);                  COMP(A0, b1);
    LOADB3(b1, p + 7); DSA3(A0, (p + 6 < 36) ? p + 6 : 0); COMP(A1, b2);
  }
  __builtin_amdgcn_s_barrier();      // all waves done reading window -> reuse for act2

  // ---- epilogue 1: out1 = BN(conv)+x(f32) -> bias/PReLU/bias; act2 -> LDS; pk = bf16(out1) ----
  u32 pk[7][2][2];
#pragma unroll
  for (int m = 0; m < 7; ++m) {
    int prow = m * 16 + lq * 4;
    int hwm = rowgrp * 112 + prow;
#pragma unroll
    for (int n = 0; n < 2; ++n) {
      int O = O0 + n * 16;
      float4 xr = *(const float4*)(x + ((size_t)(img * 256 + O) * 784 + hwm));
      float xv[4] = {xr.x, xr.y, xr.z, xr.w};
#pragma unroll
      for (int rp = 0; rp < 2; ++rp) {
        float o1v[2];
#pragma unroll
        for (int h = 0; h < 2; ++h) {
          int reg = rp * 2 + h;
          int pix = prow + reg;
          float v = acc[m][n][reg] * al1[n] + bt1[n] + xv[reg];
          float t1 = v + pA1[n];
          t1 = (t1 > 0.f) ? t1 : pS1[n] * t1;
          o1v[h] = t1 + pB1[n];
          wl[pix * 256 + (posO[n] ^ ((pix & 15) << 4))] = f2sign8(o1v[h] + p21[n]);
        }
        pk[m][n][rp] = (u32)f2b(o1v[0]) | ((u32)f2b(o1v[1]) << 16);
      }
    }
  }
#pragma unroll
  for (int m = 0; m < 7; ++m) { acc[m][0] = zero4; acc[m][1] = zero4; }

  asm volatile("s_waitcnt lgkmcnt(0)" ::: "memory");   // act2 LDS stores complete
  __builtin_amdgcn_s_barrier();

  // ---- conv1x1: 4 phases, A reg-dbuf + B 2-set rotation ----
  DSA1(A0, 0); LOADB1(b0, 0); LOADB1(b1, 1);
  DSA1(A1, 1); COMP(A0, b0); LOADB1(b0, 2);
  DSA1(A0, 2); COMP(A1, b1); LOADB1(b1, 3);
  DSA1(A1, 3); COMP(A0, b0);
  COMP(A1, b1);

  // ---- epilogue 2: out2 -> dout NCHW f32 ----
#pragma unroll
  for (int m = 0; m < 7; ++m) {
    int hwm = rowgrp * 112 + m * 16 + lq * 4;
#pragma unroll
    for (int n = 0; n < 2; ++n) {
      int O = O0 + n * 16;
      float r4v[4];
#pragma unroll
      for (int rp = 0; rp < 2; ++rp) {
        float res[2];
        res[0] = b2f((u16)(pk[m][n][rp] & 0xFFFF));
        res[1] = b2f((u16)(pk[m][n][rp] >> 16));
#pragma unroll
        for (int h = 0; h < 2; ++h) {
          int reg = rp * 2 + h;
          float v = acc[m][n][reg] * al2[n] + bt2[n] + res[h];
          float t1 = v + pA2[n];
          t1 = (t1 > 0.f) ? t1 : pS2[n] * t1;
          r4v[reg] = t1 + pB2[n];
        }
      }
      float4 r4 = {r4v[0], r4v[1], r4v[2], r4v[3]};
      *(float4*)(dout + ((size_t)(img * 256 + O)) * 784 + hwm) = r4;
    }
  }
}

// ---------------- launcher ----------------
extern "C" void kernel_launch(void* const* d_in, const int* in_sizes, int n_in,
                              void* d_out, int out_size, void* d_ws, size_t ws_size,
                              hipStream_t stream) {
  const float* x    = (const float*)d_in[0];
  const float* loss = (const float*)d_in[1];
  const float* b11  = (const float*)d_in[2];
  const float* b12  = (const float*)d_in[3];
  const float* b13  = (const float*)d_in[4];
  const float* b21  = (const float*)d_in[5];
  const float* b22  = (const float*)d_in[6];
  const float* b23  = (const float*)d_in[7];
  const float* w1   = (const float*)d_in[8];
  const float* w2   = (const float*)d_in[9];
  const float* g1   = (const float*)d_in[10];
  const float* be1  = (const float*)d_in[11];
  const float* m1   = (const float*)d_in[12];
  const float* v1   = (const float*)d_in[13];
  const float* g2   = (const float*)d_in[14];
  const float* be2  = (const float*)d_in[15];
  const float* m2   = (const float*)d_in[16];
  const float* v2   = (const float*)d_in[17];
  const float* a1   = (const float*)d_in[18];
  const float* a2   = (const float*)d_in[19];

  char* ws = (char*)d_ws;
  u8*    act1pad = (u8*)(ws + 0ull);           // fp8 (32,30,30,256) = 7,372,800
  u8*    w1T     = (u8*)(ws + 7372800ull);     // 36 phases x 16KB = 589,824
  u8*    w2T     = (u8*)(ws + 7962624ull);     // 4 phases x 16KB = 65,536
  float* ab      = (float*)(ws + 8028160ull);  // 4 x 256 f32

  float* out = (float*)d_out;

  prep_kernel<<<512, 256, 0, stream>>>(w1, w2, g1, be1, m1, v1, g2, be2, m2, v2,
                                       w1T, w2T, ab, out + (out_size - 1), loss);
  act1_kernel<<<dim3(7, 4, 32), 256, 0, stream>>>(x, b11, act1pad);
  fused_kernel<<<224, 512, 0, stream>>>(act1pad, x, w1T, w2T, ab,
                                        b12, a1, b13, b21, b22, a2, b23, out);
}

// Round 10
// 55.098 us; speedup vs baseline: 1.2994x; 1.0859x over previous
//
#include <hip/hip_runtime.h>
#include <hip/hip_bf16.h>

// BasicBlock (ReActNet) fused pipeline, MI355X gfx950.  R10 = R9 +
// (1) fused kernel __launch_bounds__(512, 1): grid is 224 (1 block/CU), so the
//     old min-waves=2 only starved registers (VGPR=88 < the ~136 live regs the
//     A/B double-buffers need) forcing serial LDS re-reads at each MFMA --
//     the ~2200cy/phase invariant. Let it have 256 VGPR.
// (2) prep + act1 merged into one kernel (branch on blockIdx) -- one less
//     launch gap; prep compute overlaps act1 bandwidth.

typedef unsigned short u16;
typedef unsigned char  u8;
typedef unsigned int   u32;
typedef unsigned long long u64;
typedef float f32x4 __attribute__((ext_vector_type(4)));
typedef long  long2v __attribute__((ext_vector_type(2)));

#define GLD16(gsrc, ldst) \
  __builtin_amdgcn_global_load_lds((__attribute__((address_space(1))) void*)(gsrc), \
                                   (__attribute__((address_space(3))) void*)(ldst), 16, 0, 0)

__device__ __forceinline__ float b2f(u16 u) {
  union { unsigned int i; float f; } c; c.i = ((unsigned int)u) << 16; return c.f;
}
__device__ __forceinline__ u16 f2b(float f) {
  unsigned int u = __builtin_bit_cast(unsigned int, f);
  unsigned int r = (u + 0x7FFFu + ((u >> 16) & 1u)) >> 16;   // RNE
  return (u16)r;
}
__device__ __forceinline__ u8 f2sign8(float v) {   // fp8 e4m3 of sign(v)
  return (v > 0.f) ? 0x38 : ((v < 0.f) ? 0xB8 : 0x00);
}

// ---- prep(blk<512) + act1(blk>=512) merged ----
// prep: fp8 sign weights phase-major [phase][c8(8)][O(256)][8B]; BN fold; loss.
// act1: NCHW f32 -> padded fp8 signs (b,30,30,256), pos-permuted channel order.
__global__ __launch_bounds__(256) void prep_act_kernel(
    const float* __restrict__ w1, const float* __restrict__ w2,
    const float* __restrict__ g1, const float* __restrict__ be1,
    const float* __restrict__ m1, const float* __restrict__ v1,
    const float* __restrict__ g2, const float* __restrict__ be2,
    const float* __restrict__ m2, const float* __restrict__ v2,
    u8* __restrict__ w1T, u8* __restrict__ w2T,
    float* __restrict__ ab,
    float* __restrict__ lossdst, const float* __restrict__ lossin,
    const float* __restrict__ x, const float* __restrict__ b11,
    u8* __restrict__ act1pad)
{
  __shared__ float wrow[2304];
  __shared__ float red[256];
  __shared__ u8 lds8[112 * 64];
  const int t = threadIdx.x;
  const int blk = blockIdx.x;

  if (blk < 512) {   // ================= prep =================
    float s = 0.f;
    if (blk < 256) {                       // w1 row o: stage coalesced, then pack
      const int o = blk;
      const float4* src = (const float4*)(w1 + o * 2304);
#pragma unroll
      for (int i = 0; i < 3; ++i) {
        int c = i * 256 + t;
        if (c < 576) {
          float4 v = src[c];
          wrow[c * 4 + 0] = v.x; wrow[c * 4 + 1] = v.y;
          wrow[c * 4 + 2] = v.z; wrow[c * 4 + 3] = v.w;
          s += fabsf(v.x) + fabsf(v.y) + fabsf(v.z) + fabsf(v.w);
        }
      }
    } else {
      const int o = blk - 256;
      float v = w2[o * 256 + t];
      wrow[t] = v;
      s = fabsf(v);
    }
    red[t] = s;
    __syncthreads();
    for (int st = 128; st > 0; st >>= 1) { if (t < st) red[t] += red[t + st]; __syncthreads(); }
    if (blk < 256) {
      const int o = blk;
      for (int it = t; it < 288; it += 256) {   // (tap, ci-octet)
        int tap = it >> 5, ci8 = it & 31;
        u64 pack = 0;
#pragma unroll
        for (int k = 0; k < 8; ++k)
          pack |= ((u64)f2sign8(wrow[(ci8 * 8 + k) * 9 + tap])) << (8 * k);
        *(u64*)(w1T + (size_t)(tap * 32 + ci8) * 2048 + o * 8) = pack;
      }
      if (t == 0) {
        float scale = red[0] / 2304.f;
        float inv = g1[o] / sqrtf(v1[o] + 1e-5f);
        ab[o]       = scale * inv;
        ab[256 + o] = be1[o] - m1[o] * inv;
      }
    } else {
      const int o = blk - 256;
      if (t < 32) {
        u64 pack = 0;
#pragma unroll
        for (int k = 0; k < 8; ++k)
          pack |= ((u64)f2sign8(wrow[t * 8 + k])) << (8 * k);
        *(u64*)(w2T + (size_t)t * 2048 + o * 8) = pack;
      }
      if (t == 0) {
        float scale = red[0] / 256.f;
        float inv = g2[o] / sqrtf(v2[o] + 1e-5f);
        ab[512 + o] = scale * inv;
        ab[768 + o] = be2[o] - m2[o] * inv;
      }
    }
    if (blk == 0 && t == 0) lossdst[0] = lossin[0];
    return;
  }

  // ================= act1 =================
  const int b2i = blk - 512;             // 0..895
  const int pxgrp = b2i % 7;
  const int cgrp  = (b2i / 7) & 3;
  const int img   = b2i / 28;
  const int c0 = cgrp * 64;
  const int p0 = pxgrp * 112;
  const float* xb = x + (size_t)img * 200704;
#pragma unroll
  for (int it = 0; it < 7; ++it) {
    int flat = it * 256 + t;           // c:64 x p4:28
    int c = flat / 28;
    int p = (flat % 28) * 4;
    float4 v4 = *(const float4*)(xb + (size_t)(c0 + c) * 784 + p0 + p);
    float bb = b11[c0 + c];
    lds8[(p + 0) * 64 + c] = f2sign8(v4.x + bb);
    lds8[(p + 1) * 64 + c] = f2sign8(v4.y + bb);
    lds8[(p + 2) * 64 + c] = f2sign8(v4.z + bb);
    lds8[(p + 3) * 64 + c] = f2sign8(v4.w + bb);
  }
  __syncthreads();
#pragma unroll
  for (int it = 0; it < 7; ++it) {
    int flat = it * 256 + t;           // px:112 x c4:16
    int px = flat >> 4;
    int c4 = (flat & 15) * 4;          // local ci, multiple of 4
    u32 v = *(const u32*)(lds8 + px * 64 + c4);
    int pos = (((c4 >> 3) & 3) << 4) | (((c4 >> 5) & 1) << 3) | (c4 & 7);  // pos-permute
    int pr = (px * 293) >> 13;         // px/28
    int pc = px - 28 * pr;
    size_t dst = ((size_t)img * 900 + (size_t)(pxgrp * 4 + 1 + pr) * 30 + 1 + pc) * 256 + c0 + pos;
    *(u32*)(act1pad + dst) = v;
  }
  if (pxgrp == 0 && cgrp == 0) {
    for (int idx = t; idx < 116 * 64; idx += 256) {
      int bp = idx >> 6;
      int l4 = (idx & 63) * 4;
      int br, bc;
      if (bp < 30)      { br = 0;       bc = bp; }
      else if (bp < 60) { br = 29;      bc = bp - 30; }
      else if (bp < 88) { br = bp - 59; bc = 0; }
      else              { br = bp - 87; bc = 29; }
      *(u32*)(act1pad + ((size_t)img * 900 + br * 30 + bc) * 256 + l4) = 0u;
    }
  }
}

// ---------------- fused conv3x3 + conv1x1, register-B, A-reg double-buffer ----------------
__global__ __launch_bounds__(512, 1) void fused_kernel(
    const u8* __restrict__ act1pad, const float* __restrict__ x,
    const u8* __restrict__ w1T, const u8* __restrict__ w2T,
    const float* __restrict__ ab,
    const float* __restrict__ b12, const float* __restrict__ a1,
    const float* __restrict__ b13, const float* __restrict__ b21,
    const float* __restrict__ b22, const float* __restrict__ a2,
    const float* __restrict__ b23,
    float* __restrict__ dout)
{
  __shared__ __align__(16) u8 win[46080];   // 180 px x 256 B; reused for act2

  const int t = threadIdx.x;
  const int w = t >> 6;
  const int l = t & 63;
  const int lane16 = l & 15;
  const int lq = l >> 4;
  const int O0 = w * 32 + lane16;
  const int pxblk = blockIdx.x;        // 224
  const int img = pxblk / 7;
  const int rowgrp = pxblk % 7;

  float al1[2], bt1[2], pA1[2], pS1[2], pB1[2], p21[2];
  float al2[2], bt2[2], pA2[2], pS2[2], pB2[2];
  int posO[2];
#pragma unroll
  for (int n = 0; n < 2; ++n) {
    int O = O0 + n * 16;
    al1[n] = ab[O];       bt1[n] = ab[256 + O];
    al2[n] = ab[512 + O]; bt2[n] = ab[768 + O];
    pA1[n] = b12[O]; pS1[n] = a1[O]; pB1[n] = b13[O]; p21[n] = b21[O];
    pA2[n] = b22[O]; pS2[n] = a2[O]; pB2[n] = b23[O];
    posO[n] = (O & 0xC0) | (((O >> 3) & 3) << 4) | (((O >> 5) & 1) << 3) | (O & 7);
  }

  int basepix[7];
#pragma unroll
  for (int m = 0; m < 7; ++m) {
    int pm = m * 16 + lane16;
    int r = (pm * 293) >> 13;          // pm/28
    basepix[m] = r * 30 + (pm - 28 * r);
  }

  char* wl = (char*)win;

  f32x4 acc[7][2];
  f32x4 zero4 = {0.f, 0.f, 0.f, 0.f};
#pragma unroll
  for (int m = 0; m < 7; ++m) { acc[m][0] = zero4; acc[m][1] = zero4; }

  // ---- prologue: stage pos-ordered window once (inverse-swizzled source) ----
  const u8* winsrc = act1pad + ((size_t)img * 900 + (size_t)rowgrp * 120) * 256;
#pragma unroll
  for (int i = 0; i < 5; ++i) {
    int c = i * 512 + t;
    int pix = c >> 4, j = c & 15;
    GLD16((const char*)winsrc + pix * 256 + ((j ^ (pix & 15)) << 4), wl + c * 16);
  }
  if (t < 320) {
    int c = 2560 + t;
    int pix = c >> 4, j = c & 15;
    GLD16((const char*)winsrc + pix * 256 + ((j ^ (pix & 15)) << 4), wl + c * 16);
  }
  asm volatile("s_waitcnt vmcnt(0)" ::: "memory");
  __builtin_amdgcn_s_barrier();

  // ---- loaders / compute primitives ----
  auto LOADB3 = [&](long* dst, int s) {
    int sc = (s < 36) ? s : 0;
    const char* base = (const char*)w1T + (size_t)sc * 16384 + lq * 2048;
#pragma unroll
    for (int n = 0; n < 2; ++n)
#pragma unroll
      for (int sl = 0; sl < 2; ++sl)
        dst[n * 2 + sl] = *(const long*)(base + sl * 8192 + (O0 + n * 16) * 8);
  };
  auto LOADB1 = [&](long* dst, int sp) {
    const char* base = (const char*)w2T + (size_t)sp * 16384 + lq * 2048;
#pragma unroll
    for (int n = 0; n < 2; ++n)
#pragma unroll
      for (int sl = 0; sl < 2; ++sl)
        dst[n * 2 + sl] = *(const long*)(base + sl * 8192 + (O0 + n * 16) * 8);
  };
  auto DSA3 = [&](long2v* dst, int s) {      // 7 x ds_read_b128, phase s
    int tap = s >> 2;
    int ti = (tap * 11) >> 5;                // tap/3
    int tapoff = ti * 30 + (tap - 3 * ti);
    int base16 = (s & 3) * 64 + lq * 16;
#pragma unroll
    for (int m = 0; m < 7; ++m) {
      int wp = basepix[m] + tapoff;
      dst[m] = *(const long2v*)(wl + wp * 256 + (base16 ^ ((wp & 15) << 4)));
    }
  };
  auto DSA1 = [&](long2v* dst, int sp) {
    int base16 = sp * 64 + lq * 16;
#pragma unroll
    for (int m = 0; m < 7; ++m) {
      int pm = m * 16 + lane16;
      dst[m] = *(const long2v*)(wl + pm * 256 + (base16 ^ ((pm & 15) << 4)));
    }
  };
  auto COMP = [&](const long2v* a, const long* bv) {
#pragma unroll
    for (int m = 0; m < 7; ++m) {
      acc[m][0] = __builtin_amdgcn_mfma_f32_16x16x32_fp8_fp8(a[m][0], bv[0], acc[m][0], 0, 0, 0);
      acc[m][1] = __builtin_amdgcn_mfma_f32_16x16x32_fp8_fp8(a[m][0], bv[2], acc[m][1], 0, 0, 0);
      acc[m][0] = __builtin_amdgcn_mfma_f32_16x16x32_fp8_fp8(a[m][1], bv[1], acc[m][0], 0, 0, 0);
      acc[m][1] = __builtin_amdgcn_mfma_f32_16x16x32_fp8_fp8(a[m][1], bv[3], acc[m][1], 0, 0, 0);
    }
  };

  // ---- conv3x3: 36 phases, A reg-dbuf + B 3-set rotation, no barriers ----
  long2v A0[7], A1[7];
  long b0[4], b1[4], b2[4];
  DSA3(A0, 0); LOADB3(b0, 0); LOADB3(b1, 1);
#pragma unroll 1
  for (int i = 0; i < 6; ++i) {
    int p = i * 6;
    LOADB3(b2, p + 2); DSA3(A1, p + 1);                  COMP(A0, b0);
    LOADB3(b0, p + 3); DSA3(A0, p + 2);                  COMP(A1, b1);
    LOADB3(b1, p + 4); DSA3(A1, p + 3);                  COMP(A0, b2);
    LOADB3(b2, p + 5); DSA3(A0, p + 4);                  COMP(A1, b0);
    LOADB3(b0, p + 6); DSA3(A1, p + 5);                  COMP(A0, b1);
    LOADB3(b1, p + 7); DSA3(A0, (p + 6 < 36) ? p + 6 : 0); COMP(A1, b2);
  }
  __builtin_amdgcn_s_barrier();      // all waves done reading window -> reuse for act2

  // ---- epilogue 1: out1 = BN(conv)+x(f32) -> bias/PReLU/bias; act2 -> LDS; pk = bf16(out1) ----
  u32 pk[7][2][2];
#pragma unroll
  for (int m = 0; m < 7; ++m) {
    int prow = m * 16 + lq * 4;
    int hwm = rowgrp * 112 + prow;
#pragma unroll
    for (int n = 0; n < 2; ++n) {
      int O = O0 + n * 16;
      float4 xr = *(const float4*)(x + ((size_t)(img * 256 + O) * 784 + hwm));
      float xv[4] = {xr.x, xr.y, xr.z, xr.w};
#pragma unroll
      for (int rp = 0; rp < 2; ++rp) {
        float o1v[2];
#pragma unroll
        for (int h = 0; h < 2; ++h) {
          int reg = rp * 2 + h;
          int pix = prow + reg;
          float v = acc[m][n][reg] * al1[n] + bt1[n] + xv[reg];
          float t1 = v + pA1[n];
          t1 = (t1 > 0.f) ? t1 : pS1[n] * t1;
          o1v[h] = t1 + pB1[n];
          wl[pix * 256 + (posO[n] ^ ((pix & 15) << 4))] = f2sign8(o1v[h] + p21[n]);
        }
        pk[m][n][rp] = (u32)f2b(o1v[0]) | ((u32)f2b(o1v[1]) << 16);
      }
    }
  }
#pragma unroll
  for (int m = 0; m < 7; ++m) { acc[m][0] = zero4; acc[m][1] = zero4; }

  asm volatile("s_waitcnt lgkmcnt(0)" ::: "memory");   // act2 LDS stores complete
  __builtin_amdgcn_s_barrier();

  // ---- conv1x1: 4 phases, A reg-dbuf + B 2-set rotation ----
  DSA1(A0, 0); LOADB1(b0, 0); LOADB1(b1, 1);
  DSA1(A1, 1); COMP(A0, b0); LOADB1(b0, 2);
  DSA1(A0, 2); COMP(A1, b1); LOADB1(b1, 3);
  DSA1(A1, 3); COMP(A0, b0);
  COMP(A1, b1);

  // ---- epilogue 2: out2 -> dout NCHW f32 ----
#pragma unroll
  for (int m = 0; m < 7; ++m) {
    int hwm = rowgrp * 112 + m * 16 + lq * 4;
#pragma unroll
    for (int n = 0; n < 2; ++n) {
      int O = O0 + n * 16;
      float r4v[4];
#pragma unroll
      for (int rp = 0; rp < 2; ++rp) {
        float res[2];
        res[0] = b2f((u16)(pk[m][n][rp] & 0xFFFF));
        res[1] = b2f((u16)(pk[m][n][rp] >> 16));
#pragma unroll
        for (int h = 0; h < 2; ++h) {
          int reg = rp * 2 + h;
          float v = acc[m][n][reg] * al2[n] + bt2[n] + res[h];
          float t1 = v + pA2[n];
          t1 = (t1 > 0.f) ? t1 : pS2[n] * t1;
          r4v[reg] = t1 + pB2[n];
        }
      }
      float4 r4 = {r4v[0], r4v[1], r4v[2], r4v[3]};
      *(float4*)(dout + ((size_t)(img * 256 + O)) * 784 + hwm) = r4;
    }
  }
}

// ---------------- launcher ----------------
extern "C" void kernel_launch(void* const* d_in, const int* in_sizes, int n_in,
                              void* d_out, int out_size, void* d_ws, size_t ws_size,
                              hipStream_t stream) {
  const float* x    = (const float*)d_in[0];
  const float* loss = (const float*)d_in[1];
  const float* b11  = (const float*)d_in[2];
  const float* b12  = (const float*)d_in[3];
  const float* b13  = (const float*)d_in[4];
  const float* b21  = (const float*)d_in[5];
  const float* b22  = (const float*)d_in[6];
  const float* b23  = (const float*)d_in[7];
  const float* w1   = (const float*)d_in[8];
  const float* w2   = (const float*)d_in[9];
  const float* g1   = (const float*)d_in[10];
  const float* be1  = (const float*)d_in[11];
  const float* m1   = (const float*)d_in[12];
  const float* v1   = (const float*)d_in[13];
  const float* g2   = (const float*)d_in[14];
  const float* be2  = (const float*)d_in[15];
  const float* m2   = (const float*)d_in[16];
  const float* v2   = (const float*)d_in[17];
  const float* a1   = (const float*)d_in[18];
  const float* a2   = (const float*)d_in[19];

  char* ws = (char*)d_ws;
  u8*    act1pad = (u8*)(ws + 0ull);           // fp8 (32,30,30,256) = 7,372,800
  u8*    w1T     = (u8*)(ws + 7372800ull);     // 36 phases x 16KB = 589,824
  u8*    w2T     = (u8*)(ws + 7962624ull);     // 4 phases x 16KB = 65,536
  float* ab      = (float*)(ws + 8028160ull);  // 4 x 256 f32

  float* out = (float*)d_out;

  prep_act_kernel<<<1408, 256, 0, stream>>>(w1, w2, g1, be1, m1, v1, g2, be2, m2, v2,
                                            w1T, w2T, ab, out + (out_size - 1), loss,
                                            x, b11, act1pad);
  fused_kernel<<<224, 512, 0, stream>>>(act1pad, x, w1T, w2T, ab,
                                        b12, a1, b13, b21, b22, a2, b23, out);
}